// Round 14
// baseline (343.945 us; speedup 1.0000x reference)
//
#include <hip/hip_runtime.h>
#include <hip/hip_fp16.h>

#define MAXD 192
#define NCH  16

#define RFL_I(x) __builtin_amdgcn_readfirstlane(x)
#define RFL_F(x) __int_as_float(__builtin_amdgcn_readfirstlane(__float_as_int(x)))
#define RDLU(v,k) ((unsigned)__builtin_amdgcn_readlane((int)(v), (k)))
#define H2(u) __builtin_bit_cast(__half2, (unsigned)(u))
#define U32(h) __builtin_bit_cast(unsigned, (h))

struct F2 { float x, y; };   // align 4: dword-aligned global pair load
#define LOADF2(base, boff) (*(const F2*)((base) + (boff)))

// One block per (point n = blockIdx.x, level j = blockIdx.y).
// Waves 0-2: pass-1 (scale 1) disparity chunks [0,64),[64,128),[128,192).
// Wave 3:   pass-0 (scale 4, D=48), level j+8.
// Wave-private LDS strips; only block-wide barrier is the val4 handoff.
// R14: branch-free iteration body with FETCH-NEUTRAL lane clamps (out-of-
// role lanes re-load already-fetched addresses; their LDS writes land in
// never-read slots or duplicate same-value writes), PLUS channel-loop
// unroll 2 so the scheduler overlaps iteration B's global loads with
// iteration A's lgkmcnt-gated taps (cross-iteration pipelining — the
// overlap R12/R13 lacked; DS in-order per wave makes LDS WAR safe).
// Packed half2 strip (2 ch/iter), pk-f16 taps, pair-loads, folded weights.
// LESSON (R5/R6/R8/R9): no long-lived register arrays; recompute row
// constants inline; WRITE_SIZE is the spill tripwire.
__global__ __launch_bounds__(256, 8) void pbm_kernel(
    const float* __restrict__ lfeat,   // (16,1,16,H,W)
    const float* __restrict__ rfeat,
    const float* __restrict__ points,  // (1,N,2)
    const int* __restrict__ pW, const int* __restrict__ pH,
    float* __restrict__ out)           // (1,N,192,8)
{
    const int W = RFL_I(*pW), H = RFL_I(*pH);
    const int HW = W * H;
    const int n   = blockIdx.x;
    const int j   = blockIdx.y;        // linear wg = n + N*j, N%8==0 -> same-n same XCD
    const int tid = threadIdx.x;
    const int wv  = tid >> 6;
    const int l   = tid & 63;

    const float pxr = points[2 * n];
    const float pyr = points[2 * n + 1];
    const float pxf = floorf(pxr), pyf = floorf(pyr);
    const float fx  = RFL_F(pxr - pxf);
    const float fy  = RFL_F(pyr - pyf);
    const int   x0i = RFL_I((int)pxf);
    const int   y0i = RFL_I((int)pyf);

    __shared__ unsigned svh[4][5][68]; // per-wave right strip, half2 (2 ch packed)
    __shared__ float    val4[48];

    const bool isP0 = (wv == 3);
    const int  s_   = RFL_I(isP0 ? 4 : 1);
    const int  lvl  = RFL_I(isP0 ? j + 8 : j);
    const int  off  = RFL_I(isP0 ? 49 : wv * 64 + 65);
    const int  DC   = RFL_I(isP0 ? 48 : 64);

    // ---- strip column consts: wave3 lanes 52-63 clamp to col 51 (dup of a
    // cached line; their writes land in unread cols 52-63) -> FETCH-neutral.
    const int   sl_   = isP0 ? min(l, 51) : l;
    const int   cx    = x0i + s_ * (sl_ - off);
    const int   pairB = min(max(cx, 0), W - 2) * 4;
    const float ax0   = (((unsigned)cx       < (unsigned)W) ? 1.0f : 0.0f) * (1.0f - fx);
    const float ax1   = (((unsigned)(cx + 1) < (unsigned)W) ? 1.0f : 0.0f) * fx;
    const float w0    = ((cx >= W - 1) ? 0.f : ax0) + ((cx >= 0) ? 0.f : ax1);
    const float w1    = ((cx >= W - 1) ? ax0 : 0.f) + ((cx >= 0) ? ax1 : 0.f);

    // ---- cleanup taps: col 64+(l&3), row min(l>>2,4). Lanes>=20 duplicate
    // lanes 16-19 (same addr, same value). Wave3 clamps its load address to
    // x0i (inside its own strip rows -> already-fetched lines); its writes
    // go to cols 64-67 which wave3 taps never read.
    const int   dyc  = min(l >> 2, 4);
    const int   dcol = 64 + (l & 3);
    const int   dcx  = isP0 ? x0i : (x0i + s_ * (dcol - off));
    const float dax0 = (((unsigned)dcx       < (unsigned)W) ? 1.0f : 0.0f) * (1.0f - fx);
    const float dax1 = (((unsigned)(dcx + 1) < (unsigned)W) ? 1.0f : 0.0f) * fx;
    const float w0d  = ((dcx >= W - 1) ? 0.f : dax0) + ((dcx >= 0) ? 0.f : dax1);
    const float w1d  = ((dcx >= W - 1) ? dax0 : 0.f) + ((dcx >= 0) ? dax1 : 0.f);
    const int   dyr  = y0i + s_ * (dyc - 2);
    const int   voA  = min(max(dyr, 0), H - 1) * (W * 4) + min(max(dcx, 0), W - 2) * 4;
    const int   voB  = min(max(dyr + 1, 0), H - 1) * (W * 4) + min(max(dcx, 0), W - 2) * 4;
    const float dwy0 = ((unsigned)dyr       < (unsigned)H) ? (1.0f - fy) : 0.0f;
    const float dwy1 = ((unsigned)(dyr + 1) < (unsigned)H) ? fy : 0.0f;

    // ---- left window taps (lanes 0..24 meaningful; 25-63 dup lane 24) ----
    const int   lq   = min(l, 24);
    const int   lyy  = lq / 5;
    const int   lxx  = lq - lyy * 5;
    const int   lx   = x0i + s_ * (lxx - 2);
    const int   ly   = y0i + s_ * (lyy - 2);
    const float lax0 = (((unsigned)lx       < (unsigned)W) ? 1.0f : 0.0f) * (1.0f - fx);
    const float lax1 = (((unsigned)(lx + 1) < (unsigned)W) ? 1.0f : 0.0f) * fx;
    const float w0l  = ((lx >= W - 1) ? 0.f : lax0) + ((lx >= 0) ? 0.f : lax1);
    const float w1l  = ((lx >= W - 1) ? lax0 : 0.f) + ((lx >= 0) ? lax1 : 0.f);
    const int   loA  = min(max(ly, 0), H - 1) * (W * 4) + min(max(lx, 0), W - 2) * 4;
    const int   loB  = min(max(ly + 1, 0), H - 1) * (W * 4) + min(max(lx, 0), W - 2) * 4;
    const float lwy0 = ((unsigned)ly       < (unsigned)H) ? (1.0f - fy) : 0.0f;
    const float lwy1 = ((unsigned)(ly + 1) < (unsigned)H) ? fy : 0.0f;

    const char* RbC = (const char*)(rfeat + (size_t)(lvl * NCH) * HW);
    const char* LbC = (const char*)(lfeat + (size_t)(lvl * NCH) * HW);

    float acc = 0.0f;
#pragma unroll 2
    for (int c = 0; c < NCH; c += 2) {
        const char* RpC0 = RbC + (size_t)c * HW * 4;
        const char* RpC1 = RpC0 + (size_t)HW * 4;
        const char* LpC0 = LbC + (size_t)c * HW * 4;
        const char* LpC1 = LpC0 + (size_t)HW * 4;

        // left window sample (all lanes)
        unsigned lpk;
        {
            F2 pa0 = LOADF2(LpC0, loA);
            F2 pb0 = LOADF2(LpC0, loB);
            F2 pa1 = LOADF2(LpC1, loA);
            F2 pb1 = LOADF2(LpC1, loB);
            float h00 = fmaf(w0l, pa0.x, w1l * pa0.y);
            float h01 = fmaf(w0l, pb0.x, w1l * pb0.y);
            float h10 = fmaf(w0l, pa1.x, w1l * pa1.y);
            float h11 = fmaf(w0l, pb1.x, w1l * pb1.y);
            lpk = U32(__floats2half2_rn(fmaf(lwy0, h00, lwy1 * h01),
                                        fmaf(lwy0, h10, lwy1 * h11)));
        }

        // cleanup cols 64-67 (all lanes; dups/garbage benign per header)
        {
            F2 pa0 = LOADF2(RpC0, voA);
            F2 pb0 = LOADF2(RpC0, voB);
            F2 pa1 = LOADF2(RpC1, voA);
            F2 pb1 = LOADF2(RpC1, voB);
            float h00 = fmaf(w0d, pa0.x, w1d * pa0.y);
            float h01 = fmaf(w0d, pb0.x, w1d * pb0.y);
            float h10 = fmaf(w0d, pa1.x, w1d * pa1.y);
            float h11 = fmaf(w0d, pb1.x, w1d * pb1.y);
            svh[wv][dyc][dcol] = U32(__floats2half2_rn(fmaf(dwy0, h00, dwy1 * h01),
                                                       fmaf(dwy0, h10, dwy1 * h11)));
        }

        // strip rows (all lanes; wave3 cols 52-63 hold dup values, never read)
#pragma unroll 1
        for (int yy = 0; yy < 5; ++yy) {
            int   yr   = y0i + s_ * (yy - 2);          // uniform -> SALU
            int   rbB0 = min(max(yr, 0), H - 1) * (W * 4);
            int   rbB1 = min(max(yr + 1, 0), H - 1) * (W * 4);
            float wy0  = ((unsigned)yr       < (unsigned)H) ? (1.0f - fy) : 0.0f;
            float wy1  = ((unsigned)(yr + 1) < (unsigned)H) ? fy : 0.0f;
            F2 a0 = LOADF2(RpC0 + rbB0, pairB);
            F2 b0 = LOADF2(RpC0 + rbB1, pairB);
            F2 a1 = LOADF2(RpC1 + rbB0, pairB);
            F2 b1 = LOADF2(RpC1 + rbB1, pairB);
            float h00 = fmaf(w0, a0.x, w1 * a0.y);
            float h01 = fmaf(w0, b0.x, w1 * b0.y);
            float h10 = fmaf(w0, a1.x, w1 * a1.y);
            float h11 = fmaf(w0, b1.x, w1 * b1.y);
            svh[wv][yy][l] = U32(__floats2half2_rn(fmaf(wy0, h00, wy1 * h01),
                                                   fmaf(wy0, h10, wy1 * h11)));
        }

        // taps (all lanes; wave3 lanes 48-63 read in-bounds junk, acc unused)
        {
            __half2 aE = __floats2half2_rn(0.f, 0.f);
            __half2 aO = __floats2half2_rn(0.f, 0.f);
#define TAPROW(YY) {                                                        \
            const unsigned* rp = &svh[wv][YY][0] + (DC - 1 - l);            \
            unsigned q0 = rp[0], q1 = rp[1], q2 = rp[2], q3 = rp[3], q4 = rp[4];\
            unsigned s0 = RDLU(lpk, (YY)*5+0);                              \
            unsigned s1 = RDLU(lpk, (YY)*5+1);                              \
            unsigned s2 = RDLU(lpk, (YY)*5+2);                              \
            unsigned s3 = RDLU(lpk, (YY)*5+3);                              \
            unsigned s4 = RDLU(lpk, (YY)*5+4);                              \
            aE = __hadd2(aE, __habs2(__hsub2(H2(s0), H2(q0))));             \
            aO = __hadd2(aO, __habs2(__hsub2(H2(s1), H2(q1))));             \
            aE = __hadd2(aE, __habs2(__hsub2(H2(s2), H2(q2))));             \
            aO = __hadd2(aO, __habs2(__hsub2(H2(s3), H2(q3))));             \
            aE = __hadd2(aE, __habs2(__hsub2(H2(s4), H2(q4)))); }
            TAPROW(0)
            TAPROW(1)
            TAPROW(2)
            TAPROW(3)
            TAPROW(4)
#undef TAPROW
            __half2 at = __hadd2(aE, aO);
            acc += __half2float(__low2half(at)) + __half2float(__high2half(at));
        }
    }

    if (isP0 && l < 48)
        val4[l] = 1.0f - expf(-acc * (1.0f / 400.0f));

    __syncthreads();                     // the ONLY block-wide barrier

    if (tid < MAXD) {                    // waves 0-2: d == tid
        float v1  = 1.0f - expf(-acc * (1.0f / 400.0f));
        float pos = (float)tid * (47.0f / 191.0f);
        float i0f = floorf(pos);
        int   i0  = (int)i0f;
        float w   = pos - i0f;
        int   i1  = min(i0 + 1, 47);
        float up  = val4[i0] + w * (val4[i1] - val4[i0]);
        out[((size_t)n * MAXD + tid) * 8 + j] = v1 + up;
    }
}

extern "C" void kernel_launch(void* const* d_in, const int* in_sizes, int n_in,
                              void* d_out, int out_size, void* d_ws, size_t ws_size,
                              hipStream_t stream) {
    const float* lf  = (const float*)d_in[0];
    const float* rf  = (const float*)d_in[1];
    const float* pts = (const float*)d_in[2];
    const int*   pW  = (const int*)d_in[3];
    const int*   pH  = (const int*)d_in[4];
    float* out = (float*)d_out;

    const int N = in_sizes[2] / 2;       // (B=1, N, 2)
    pbm_kernel<<<dim3(N, 8), 256, 0, stream>>>(lf, rf, pts, pW, pH, out);
}

// Round 15
// 207.411 us; speedup vs baseline: 1.6583x; 1.6583x over previous
//
#include <hip/hip_runtime.h>
#include <hip/hip_fp16.h>

#define MAXD 192
#define NCH  16

#define RFL_I(x) __builtin_amdgcn_readfirstlane(x)
#define RFL_F(x) __int_as_float(__builtin_amdgcn_readfirstlane(__float_as_int(x)))
#define RDLU(v,k) ((unsigned)__builtin_amdgcn_readlane((int)(v), (k)))
#define H2(u) __builtin_bit_cast(__half2, (unsigned)(u))
#define U32(h) __builtin_bit_cast(unsigned, (h))

struct F2 { float x, y; };   // align 4: dword-aligned global pair load
#define LOADF2(base, boff) (*(const F2*)((base) + (boff)))

// One block per (level j = blockIdx.x, point n = blockIdx.y).
//   wgid = j + 8*n  ->  XCD = wgid % 8 = j: each XCD's read working set is
//   ONE level pair {j, j+8} (~7.9 MB) instead of all 16 levels (126 MB).
//   R4's FETCH=132MB (vs 214-275MB for n-major grids) validated this.
// Waves 0-2: pass-1 (scale 1) disparity chunks [0,64),[64,128),[128,192).
// Wave 3:   pass-0 (scale 4, D=48), level j+8.
// Wave-private LDS strips; only block-wide barrier is the val4 handoff.
// TWO channels per iteration, strip packed as half2 in LDS; pk-f16 taps;
// packed readlane broadcast; bilinear x-corners via dwordx2 pair-load with
// clamp-select + validity folded into loop-invariant weights (w0,w1).
// LESSON (R5/R6/R8/R9/R14): no long-lived register arrays, no channel-loop
// unrolling, recompute row constants inline; WRITE_SIZE = spill tripwire.
__global__ __launch_bounds__(256, 8) void pbm_kernel(
    const float* __restrict__ lfeat,   // (16,1,16,H,W)
    const float* __restrict__ rfeat,
    const float* __restrict__ points,  // (1,N,2)
    const int* __restrict__ pW, const int* __restrict__ pH,
    float* __restrict__ out)           // (1,N,192,8)
{
    const int W = RFL_I(*pW), H = RFL_I(*pH);
    const int HW = W * H;
    const int j   = blockIdx.x;        // XCD = j
    const int n   = blockIdx.y;
    const int tid = threadIdx.x;
    const int wv  = tid >> 6;
    const int l   = tid & 63;

    const float pxr = points[2 * n];
    const float pyr = points[2 * n + 1];
    const float pxf = floorf(pxr), pyf = floorf(pyr);
    const float fx  = RFL_F(pxr - pxf);
    const float fy  = RFL_F(pyr - pyf);
    const int   x0i = RFL_I((int)pxf);
    const int   y0i = RFL_I((int)pyf);

    __shared__ unsigned svh[4][5][68]; // per-wave right strip, half2 (2 ch packed)
    __shared__ float    val4[48];

    const bool isP0   = (wv == 3);
    const int  s_     = RFL_I(isP0 ? 4 : 1);
    const int  lvl    = RFL_I(isP0 ? j + 8 : j);
    const int  off    = RFL_I(isP0 ? 49 : wv * 64 + 65);
    const int  DC     = RFL_I(isP0 ? 48 : 64);
    const int  stageN = RFL_I(isP0 ? 52 : 64);

    // ---- strip column constants (col == lane): pair offset + folded weights
    const int   cx    = x0i + s_ * (l - off);
    const int   pairB = min(max(cx, 0), W - 2) * 4;
    const float ax0   = (((unsigned)cx       < (unsigned)W) ? 1.0f : 0.0f) * (1.0f - fx);
    const float ax1   = (((unsigned)(cx + 1) < (unsigned)W) ? 1.0f : 0.0f) * fx;
    const float w0    = ((cx >= W - 1) ? 0.f : ax0) + ((cx >= 0) ? 0.f : ax1);
    const float w1    = ((cx >= W - 1) ? ax0 : 0.f) + ((cx >= 0) ? ax1 : 0.f);

    // ---- cleanup taps (pass-1 waves, lanes<20): col 64+(l&3), row l>>2 ----
    const int   dyc  = min(l >> 2, 4);
    const int   dcol = 64 + (l & 3);
    const int   dcx  = x0i + s_ * (dcol - off);
    const float dax0 = (((unsigned)dcx       < (unsigned)W) ? 1.0f : 0.0f) * (1.0f - fx);
    const float dax1 = (((unsigned)(dcx + 1) < (unsigned)W) ? 1.0f : 0.0f) * fx;
    const float w0d  = ((dcx >= W - 1) ? 0.f : dax0) + ((dcx >= 0) ? 0.f : dax1);
    const float w1d  = ((dcx >= W - 1) ? dax0 : 0.f) + ((dcx >= 0) ? dax1 : 0.f);
    const int   dyr  = y0i + s_ * (dyc - 2);
    const int   voA  = min(max(dyr, 0), H - 1) * (W * 4) + min(max(dcx, 0), W - 2) * 4;
    const int   voB  = min(max(dyr + 1, 0), H - 1) * (W * 4) + min(max(dcx, 0), W - 2) * 4;
    const float dwy0 = ((unsigned)dyr       < (unsigned)H) ? (1.0f - fy) : 0.0f;
    const float dwy1 = ((unsigned)(dyr + 1) < (unsigned)H) ? fy : 0.0f;

    // ---- left window taps (lanes 0..24 meaningful) ----
    const int   lq   = min(l, 24);
    const int   lyy  = lq / 5;
    const int   lxx  = lq - lyy * 5;
    const int   lx   = x0i + s_ * (lxx - 2);
    const int   ly   = y0i + s_ * (lyy - 2);
    const float lax0 = (((unsigned)lx       < (unsigned)W) ? 1.0f : 0.0f) * (1.0f - fx);
    const float lax1 = (((unsigned)(lx + 1) < (unsigned)W) ? 1.0f : 0.0f) * fx;
    const float w0l  = ((lx >= W - 1) ? 0.f : lax0) + ((lx >= 0) ? 0.f : lax1);
    const float w1l  = ((lx >= W - 1) ? lax0 : 0.f) + ((lx >= 0) ? lax1 : 0.f);
    const int   loA  = min(max(ly, 0), H - 1) * (W * 4) + min(max(lx, 0), W - 2) * 4;
    const int   loB  = min(max(ly + 1, 0), H - 1) * (W * 4) + min(max(lx, 0), W - 2) * 4;
    const float lwy0 = ((unsigned)ly       < (unsigned)H) ? (1.0f - fy) : 0.0f;
    const float lwy1 = ((unsigned)(ly + 1) < (unsigned)H) ? fy : 0.0f;

    const char* RbC = (const char*)(rfeat + (size_t)(lvl * NCH) * HW);
    const char* LbC = (const char*)(lfeat + (size_t)(lvl * NCH) * HW);

    float acc = 0.0f;
#pragma unroll 1
    for (int c = 0; c < NCH; c += 2) {
        const char* RpC0 = RbC + (size_t)c * HW * 4;
        const char* RpC1 = RpC0 + (size_t)HW * 4;
        const char* LpC0 = LbC + (size_t)c * HW * 4;
        const char* LpC1 = LpC0 + (size_t)HW * 4;

        if (l < stageN) {
#pragma unroll 1
            for (int yy = 0; yy < 5; ++yy) {
                int   yr   = y0i + s_ * (yy - 2);          // uniform -> SALU
                int   rbB0 = min(max(yr, 0), H - 1) * (W * 4);
                int   rbB1 = min(max(yr + 1, 0), H - 1) * (W * 4);
                float wy0  = ((unsigned)yr       < (unsigned)H) ? (1.0f - fy) : 0.0f;
                float wy1  = ((unsigned)(yr + 1) < (unsigned)H) ? fy : 0.0f;
                F2 a0 = LOADF2(RpC0 + rbB0, pairB);
                F2 b0 = LOADF2(RpC0 + rbB1, pairB);
                F2 a1 = LOADF2(RpC1 + rbB0, pairB);
                F2 b1 = LOADF2(RpC1 + rbB1, pairB);
                float h00 = fmaf(w0, a0.x, w1 * a0.y);
                float h01 = fmaf(w0, b0.x, w1 * b0.y);
                float h10 = fmaf(w0, a1.x, w1 * a1.y);
                float h11 = fmaf(w0, b1.x, w1 * b1.y);
                float rx = fmaf(wy0, h00, wy1 * h01);
                float ry = fmaf(wy0, h10, wy1 * h11);
                svh[wv][yy][l] = U32(__floats2half2_rn(rx, ry));
            }
        }
        if (!isP0 && l < 20) {
            F2 pa0 = LOADF2(RpC0, voA);
            F2 pb0 = LOADF2(RpC0, voB);
            F2 pa1 = LOADF2(RpC1, voA);
            F2 pb1 = LOADF2(RpC1, voB);
            float h00 = fmaf(w0d, pa0.x, w1d * pa0.y);
            float h01 = fmaf(w0d, pb0.x, w1d * pb0.y);
            float h10 = fmaf(w0d, pa1.x, w1d * pa1.y);
            float h11 = fmaf(w0d, pb1.x, w1d * pb1.y);
            float rx = fmaf(dwy0, h00, dwy1 * h01);
            float ry = fmaf(dwy0, h10, dwy1 * h11);
            svh[wv][dyc][dcol] = U32(__floats2half2_rn(rx, ry));
        }
        unsigned lpk;
        {
            F2 pa0 = LOADF2(LpC0, loA);
            F2 pb0 = LOADF2(LpC0, loB);
            F2 pa1 = LOADF2(LpC1, loA);
            F2 pb1 = LOADF2(LpC1, loB);
            float h00 = fmaf(w0l, pa0.x, w1l * pa0.y);
            float h01 = fmaf(w0l, pb0.x, w1l * pb0.y);
            float h10 = fmaf(w0l, pa1.x, w1l * pa1.y);
            float h11 = fmaf(w0l, pb1.x, w1l * pb1.y);
            float lval0 = fmaf(lwy0, h00, lwy1 * h01);
            float lval1 = fmaf(lwy0, h10, lwy1 * h11);
            lpk = U32(__floats2half2_rn(lval0, lval1));
        }

        if (l < DC) {
            __half2 aE = __floats2half2_rn(0.f, 0.f);
            __half2 aO = __floats2half2_rn(0.f, 0.f);
#define TAPROW(YY) {                                                        \
            const unsigned* rp = &svh[wv][YY][DC - 1 - l];                  \
            unsigned q0 = rp[0], q1 = rp[1], q2 = rp[2], q3 = rp[3], q4 = rp[4];\
            unsigned s0 = RDLU(lpk, (YY)*5+0);                              \
            unsigned s1 = RDLU(lpk, (YY)*5+1);                              \
            unsigned s2 = RDLU(lpk, (YY)*5+2);                              \
            unsigned s3 = RDLU(lpk, (YY)*5+3);                              \
            unsigned s4 = RDLU(lpk, (YY)*5+4);                              \
            aE = __hadd2(aE, __habs2(__hsub2(H2(s0), H2(q0))));             \
            aO = __hadd2(aO, __habs2(__hsub2(H2(s1), H2(q1))));             \
            aE = __hadd2(aE, __habs2(__hsub2(H2(s2), H2(q2))));             \
            aO = __hadd2(aO, __habs2(__hsub2(H2(s3), H2(q3))));             \
            aE = __hadd2(aE, __habs2(__hsub2(H2(s4), H2(q4)))); }
            TAPROW(0)
            TAPROW(1)
            TAPROW(2)
            TAPROW(3)
            TAPROW(4)
#undef TAPROW
            __half2 at = __hadd2(aE, aO);
            acc += __half2float(__low2half(at)) + __half2float(__high2half(at));
        }
    }

    if (isP0 && l < 48)
        val4[l] = 1.0f - expf(-acc * (1.0f / 400.0f));

    __syncthreads();                     // the ONLY block-wide barrier

    if (tid < MAXD) {                    // waves 0-2: d == tid
        float v1  = 1.0f - expf(-acc * (1.0f / 400.0f));
        float pos = (float)tid * (47.0f / 191.0f);
        float i0f = floorf(pos);
        int   i0  = (int)i0f;
        float w   = pos - i0f;
        int   i1  = min(i0 + 1, 47);
        float up  = val4[i0] + w * (val4[i1] - val4[i0]);
        out[((size_t)n * MAXD + tid) * 8 + j] = v1 + up;
    }
}

extern "C" void kernel_launch(void* const* d_in, const int* in_sizes, int n_in,
                              void* d_out, int out_size, void* d_ws, size_t ws_size,
                              hipStream_t stream) {
    const float* lf  = (const float*)d_in[0];
    const float* rf  = (const float*)d_in[1];
    const float* pts = (const float*)d_in[2];
    const int*   pW  = (const int*)d_in[3];
    const int*   pH  = (const int*)d_in[4];
    float* out = (float*)d_out;

    const int N = in_sizes[2] / 2;       // (B=1, N, 2)
    pbm_kernel<<<dim3(8, N), 256, 0, stream>>>(lf, rf, pts, pW, pH, out);
}